// Round 2
// baseline (417.806 us; speedup 1.0000x reference)
//
#include <hip/hip_runtime.h>
#include <cstdint>
#include <cstddef>

// Dtypes PROVEN fp32 (R2 bf16-read -> NaN; R4 fp32-read -> pass, absmax 0.0078).
#define N_NODES 8192
#define FIN 256
#define FOUT 128
#define MT 32                 // rows per block in gat kernel
#define KC 256                // j-chunk size
#define JS 4                  // j slices (partial softmax, merged in fin_kernel)
#define JW (N_NODES / JS)     // 2048 columns per slice
#define NCHS (JW / KC)        // 8 chunks per block
#define LOG2E 1.4426950408889634f

typedef __attribute__((ext_vector_type(8))) short bf16x8;
typedef __attribute__((ext_vector_type(4))) float f32x4;
typedef __attribute__((ext_vector_type(4))) int i32x4;
typedef __attribute__((ext_vector_type(2))) unsigned int u32x2;

__device__ __forceinline__ float bf2f(unsigned short u) {
    union { unsigned int i; float f; } v; v.i = ((unsigned int)u) << 16; return v.f;
}
__device__ __forceinline__ unsigned short f2bf(float f) {
    union { float f; unsigned int i; } v; v.f = f;
    unsigned int r = (v.i + 0x7FFFu + ((v.i >> 16) & 1u)) >> 16;
    return (unsigned short)r;
}
__device__ __forceinline__ unsigned int pack_bf16(float a, float b) {
    return (unsigned)f2bf(a) | ((unsigned)f2bf(b) << 16);
}

// whB fragment-order layout: tile (kb, fb) holds Wh[j=kb*32+quad*8+e][f=fb*16+sl]
// at element ((kb*8+fb)*512 + (quad*16+sl)*8 + e) -> a wave's B-load is one
// contiguous 1 KB burst.
__device__ __forceinline__ size_t whb_idx(int j, int f) {
    return ((size_t)((j >> 5) * 8 + (f >> 4)) << 9) + (((j >> 3) & 3) << 7)
         + ((f & 15) << 3) + (j & 7);
}

// ---------------- Kernel A: whB = fragment-ordered bf16 (h @ W^T) -------------
__global__ __launch_bounds__(256) void wh_kernel(const float* __restrict__ h,
                                                 const float* __restrict__ W,
                                                 unsigned short* __restrict__ whB) {
    __shared__ float hT[64][FIN + 5];   // stride 261 (odd)
    const int t = threadIdx.x;
    const int i0 = blockIdx.x * 64;
    const int f0 = blockIdx.y * 32;
#pragma unroll
    for (int c = 0; c < 16; ++c) {       // 64x256 floats, float4-coalesced
        int chunk = c * 256 + t;
        int row = chunk >> 6, col = (chunk & 63) * 4;
        f32x4 v = *(const f32x4*)&h[(size_t)(i0 + row) * FIN + col];
        hT[row][col] = v[0]; hT[row][col + 1] = v[1];
        hT[row][col + 2] = v[2]; hT[row][col + 3] = v[3];
    }
    __syncthreads();
    const int lane = t & 63;
    const int fb8 = __builtin_amdgcn_readfirstlane(f0 + (t >> 6) * 8); // wave -> 8 f
    const float* w0 = W + (size_t)fb8 * FIN;
    float acc[8] = {0.f, 0.f, 0.f, 0.f, 0.f, 0.f, 0.f, 0.f};
    for (int k = 0; k < FIN; k += 4) {
        float h0 = hT[lane][k],     h1 = hT[lane][k + 1];
        float h2 = hT[lane][k + 2], h3 = hT[lane][k + 3];
#pragma unroll
        for (int c = 0; c < 8; ++c) {
            const float* wr = w0 + c * FIN;   // uniform -> s_load
            acc[c] += h0 * wr[k] + h1 * wr[k + 1] + h2 * wr[k + 2] + h3 * wr[k + 3];
        }
    }
    const int i = i0 + lane;
#pragma unroll
    for (int c = 0; c < 8; ++c)
        whB[whb_idx(i, fb8 + c)] = f2bf(acc[c]);
}

// ---------------- Kernel B: s1'[i], s2'[i] = (Wh@a)*log2e --------------------
__global__ __launch_bounds__(256) void s_kernel(const unsigned short* __restrict__ whB,
                                                const float* __restrict__ a1,
                                                const float* __restrict__ a2,
                                                float* __restrict__ s1,
                                                float* __restrict__ s2) {
    __shared__ float p1[4][64], p2[4][64];
    const int t = threadIdx.x;
    const int l = t & 63;
    const int g = t >> 6;
    const int i = blockIdx.x * 64 + l;
    float acc1 = 0.f, acc2 = 0.f;
#pragma unroll
    for (int fb = g * 2; fb < g * 2 + 2; ++fb) {
#pragma unroll
        for (int sl = 0; sl < 16; ++sl) {
            int f = fb * 16 + sl;
            float v = bf2f(whB[whb_idx(i, f)]);
            acc1 += v * a1[f];
            acc2 += v * a2[f];
        }
    }
    p1[g][l] = acc1; p2[g][l] = acc2;
    __syncthreads();
    if (g == 0) {
        s1[i] = (p1[0][l] + p1[1][l] + p1[2][l] + p1[3][l]) * LOG2E;
        s2[i] = (p2[0][l] + p2[1][l] + p2[2][l] + p2[3][l]) * LOG2E;
    }
}

// ---------------- Kernel C: fused mask+softmax-partial+PV MFMA ----------------
// grid 1024 (= 256 i-blocks x 4 j-slices), 4 blocks/CU. 32 rows/block.
// adj consumed DIRECTLY as int32. P-build mapping: wave w owns rows w*8+e
// (e=0..7); lane l owns cols l*4..l*4+3 -> every adj dwordx4 is one fully
// lane-contiguous 1 KB row-segment (16 cache lines, perfect coalescing).
// Next chunk's adj/s2 issued before the MFMA phase (latency hidden under
// barrier+MFMA+barrier). den accumulated per-lane, reduced once at the end.
__global__ __launch_bounds__(256, 4) void gat_kernel(const int* __restrict__ adj,
                                                  const unsigned short* __restrict__ whB,
                                                  const float* __restrict__ s1,
                                                  const float* __restrict__ s2,
                                                  float* __restrict__ out,     // slice-0 num
                                                  float* __restrict__ nums,    // slices 1..3
                                                  float* __restrict__ dens) {  // 4 x N
    __shared__ __align__(16) unsigned short sP[MT][KC + 8];
    const int t = threadIdx.x;
    const int slice = blockIdx.x & (JS - 1);
    const int i0 = (blockIdx.x >> 2) * MT;
    const int jb = slice * JW;
    const int kb0 = slice * (JW / 32);
    float* __restrict__ num = slice ? (nums + (size_t)(slice - 1) * N_NODES * FOUT) : out;
    float* __restrict__ den = dens + (size_t)slice * N_NODES;

    const int lane = t & 63;
    const int wv = t >> 6;       // wave id: P-rows wv*8..wv*8+7; MFMA f-pair wv*2
    const int quad = lane >> 4;
    const int sl = lane & 15;

    // s1 for this wave's 8 rows (wave-uniform -> scalar loads), exp2 domain
    float s1r[8];
#pragma unroll
    for (int e = 0; e < 8; ++e) s1r[e] = s1[i0 + wv * 8 + e];

    const int* __restrict__ aBase = adj + (size_t)(i0 + wv * 8) * N_NODES + jb + lane * 4;

    f32x4 acc00 = {0.f,0.f,0.f,0.f}, acc01 = {0.f,0.f,0.f,0.f};
    f32x4 acc10 = {0.f,0.f,0.f,0.f}, acc11 = {0.f,0.f,0.f,0.f};
    float denAcc[8] = {0.f,0.f,0.f,0.f,0.f,0.f,0.f,0.f};

    // ---- prefetch chunk 0: 8 row-segments (1 KB each, perfectly coalesced) --
    i32x4 av[8];
    f32x4 sv;
#pragma unroll
    for (int e = 0; e < 8; ++e) av[e] = *(const i32x4*)(aBase + (size_t)e * N_NODES);
    sv = *(const f32x4*)&s2[jb + lane * 4];

    for (int ch = 0; ch < NCHS; ++ch) {
        // ---- build P tile (bf16, exp2 domain) + per-lane den partials ----
#pragma unroll
        for (int e = 0; e < 8; ++e) {
            float p[4];
#pragma unroll
            for (int r = 0; r < 4; ++r) {
                float y = s1r[e] + sv[r];
                y = fmaxf(y, 0.2f * y);
                float ev = __builtin_amdgcn_exp2f(y);
                p[r] = (av[e][r] > 0) ? ev : 0.f;
                denAcc[e] += p[r];
            }
            u32x2 pk;
            pk.x = pack_bf16(p[0], p[1]);
            pk.y = pack_bf16(p[2], p[3]);
            // dword-contiguous across lanes (dwords 0..127): conflict-free b64
            *(u32x2*)&sP[wv * 8 + e][lane * 4] = pk;
        }
        // ---- prefetch next chunk (flies across barrier + MFMA + barrier) ----
        if (ch + 1 < NCHS) {
            const int* an = aBase + (ch + 1) * KC;
#pragma unroll
            for (int e = 0; e < 8; ++e) av[e] = *(const i32x4*)(an + (size_t)e * N_NODES);
            sv = *(const f32x4*)&s2[jb + (ch + 1) * KC + lane * 4];
        }
        __syncthreads();
        // ---- MFMA: NUM[32 x 128] += P[32 x 256] @ Wh[256 x 128] ----
#pragma unroll
        for (int kq = 0; kq < KC / 32; ++kq) {
            bf16x8 a0  = *(const bf16x8*)&sP[sl][kq * 32 + quad * 8];
            bf16x8 a1f = *(const bf16x8*)&sP[16 + sl][kq * 32 + quad * 8];
            int kb = kb0 + ch * (KC / 32) + kq;
            const unsigned short* t0 = whB + ((size_t)(kb * 8 + wv * 2) << 9) + lane * 8;
            bf16x8 b0 = *(const bf16x8*)t0;          // contiguous 1 KB per wave
            bf16x8 b1 = *(const bf16x8*)(t0 + 512);
            acc00 = __builtin_amdgcn_mfma_f32_16x16x32_bf16(a0,  b0, acc00, 0, 0, 0);
            acc01 = __builtin_amdgcn_mfma_f32_16x16x32_bf16(a0,  b1, acc01, 0, 0, 0);
            acc10 = __builtin_amdgcn_mfma_f32_16x16x32_bf16(a1f, b0, acc10, 0, 0, 0);
            acc11 = __builtin_amdgcn_mfma_f32_16x16x32_bf16(a1f, b1, acc11, 0, 0, 0);
        }
        __syncthreads();
    }
    // ---- den: reduce per-lane partials across the wave, once ----
#pragma unroll
    for (int e = 0; e < 8; ++e) {
        float v = denAcc[e];
        v += __shfl_xor(v, 1);  v += __shfl_xor(v, 2);  v += __shfl_xor(v, 4);
        v += __shfl_xor(v, 8);  v += __shfl_xor(v, 16); v += __shfl_xor(v, 32);
        if (lane == 0) den[i0 + wv * 8 + e] = v;
    }
    // ---- epilogue: raw partials (divide + ELU in fin_kernel) ----
#pragma unroll
    for (int m = 0; m < 2; ++m) {
#pragma unroll
        for (int nn = 0; nn < 2; ++nn) {
            f32x4 a = (m == 0) ? (nn == 0 ? acc00 : acc01) : (nn == 0 ? acc10 : acc11);
#pragma unroll
            for (int r = 0; r < 4; ++r) {
                int row = m * 16 + quad * 4 + r;     // D row=(lane>>4)*4+reg, col=lane&15
                num[(size_t)(i0 + row) * FOUT + wv * 32 + nn * 16 + sl] = a[r];
            }
        }
    }
}

// ---------------- Kernel D: merge 4 slices, divide, ELU (in-place) -----------
__global__ __launch_bounds__(256) void fin_kernel(float* __restrict__ out,      // = num0
                                                  const float* __restrict__ nums,
                                                  const float* __restrict__ dens) {
    const int idx = blockIdx.x * 256 + threadIdx.x;
    const int i = idx >> 7;                         // FOUT = 128
    const size_t NF = (size_t)N_NODES * FOUT;
    float numv = out[idx] + nums[idx] + nums[NF + idx] + nums[2 * NF + idx];
    float denv = dens[i] + dens[N_NODES + i] + dens[2 * N_NODES + i] + dens[3 * N_NODES + i];
    float v = numv / fmaxf(denv, 1e-30f);
    out[idx] = (v > 0.f) ? v : expm1f(v);
}

extern "C" void kernel_launch(void* const* d_in, const int* in_sizes, int n_in,
                              void* d_out, int out_size, void* d_ws, size_t ws_size,
                              hipStream_t stream) {
    const float* h   = (const float*)d_in[0];
    const int*   adj = (const int*)d_in[1];
    const float* W   = (const float*)d_in[2];
    const float* a1  = (const float*)d_in[3];
    const float* a2  = (const float*)d_in[4];

    // d_ws layout (ws is 1 GiB per the harness fill; we use ~17 MB):
    //   [0, 2MB)    whB (bf16, fragment-ordered)
    //   [4MB..)     s1 | s2 | dens(4xN) | nums(3 x N*FOUT)
    char* ws = (char*)d_ws;
    unsigned short* whB = (unsigned short*)ws;
    float* s1   = (float*)(ws + (4u << 20));
    float* s2   = s1 + N_NODES;
    float* dens = s2 + N_NODES;
    float* nums = dens + 4 * N_NODES;
    float* out  = (float*)d_out;

    wh_kernel<<<dim3(N_NODES / 64, FOUT / 32), 256, 0, stream>>>(h, W, whB);
    s_kernel<<<dim3(N_NODES / 64), 256, 0, stream>>>(whB, a1, a2, s1, s2);
    gat_kernel<<<dim3((N_NODES / MT) * JS), 256, 0, stream>>>(adj, whB, s1, s2,
                                                              out, nums, dens);
    fin_kernel<<<dim3(N_NODES * FOUT / 256), 256, 0, stream>>>(out, nums, dens);
}

// Round 3
// 403.523 us; speedup vs baseline: 1.0354x; 1.0354x over previous
//
#include <hip/hip_runtime.h>
#include <cstdint>
#include <cstddef>

// Dtypes PROVEN fp32 (R2 bf16-read -> NaN; R4 fp32-read -> pass, absmax 0.0078).
#define N_NODES 8192
#define FIN 256
#define FOUT 128
#define MT 32                 // rows per block in gat kernel
#define KC 256                // j-chunk size
#define JS 4                  // j slices (partial softmax, merged in fin_kernel)
#define JW (N_NODES / JS)     // 2048 columns per slice
#define NCHS (JW / KC)        // 8 chunks per block
#define LOG2E 1.4426950408889634f

typedef __attribute__((ext_vector_type(8))) short bf16x8;
typedef __attribute__((ext_vector_type(4))) float f32x4;
typedef __attribute__((ext_vector_type(4))) int i32x4;
typedef __attribute__((ext_vector_type(2))) unsigned int u32x2;
typedef __attribute__((ext_vector_type(4))) unsigned int u32x4;

__device__ __forceinline__ float bf2f(unsigned short u) {
    union { unsigned int i; float f; } v; v.i = ((unsigned int)u) << 16; return v.f;
}
__device__ __forceinline__ unsigned short f2bf(float f) {
    union { float f; unsigned int i; } v; v.f = f;
    unsigned int r = (v.i + 0x7FFFu + ((v.i >> 16) & 1u)) >> 16;
    return (unsigned short)r;
}
__device__ __forceinline__ unsigned int pack_bf16(float a, float b) {
    return (unsigned)f2bf(a) | ((unsigned)f2bf(b) << 16);
}

// whB fragment-order layout: tile (kb, fb) holds Wh[j=kb*32+quad*8+e][f=fb*16+sl]
// at element ((kb*8+fb)*512 + (quad*16+sl)*8 + e) -> a wave's B-load is one
// contiguous 1 KB burst.
__device__ __forceinline__ size_t whb_idx(int j, int f) {
    return ((size_t)((j >> 5) * 8 + (f >> 4)) << 9) + (((j >> 3) & 3) << 7)
         + ((f & 15) << 3) + (j & 7);
}

// ---------------- Kernel Z: zero s1|s2 (atomic targets) ----------------------
__global__ __launch_bounds__(256) void zs_kernel(float* __restrict__ s12) {
    const int idx = blockIdx.x * 256 + threadIdx.x;     // 16 blocks: 16384 floats
    f32x4 z = {0.f, 0.f, 0.f, 0.f};
    *(f32x4*)&s12[idx * 4] = z;
}

// ---------------- Kernel A: whB = fragment-ordered bf16 (h @ W^T) -------------
// Also fuses the s-pass: s1/s2 partials from the in-register acc[8], LDS-reduced
// across the block's 4 waves, then one atomicAdd per (node, f-block).
__global__ __launch_bounds__(256) void wh_kernel(const float* __restrict__ h,
                                                 const float* __restrict__ W,
                                                 const float* __restrict__ a1,
                                                 const float* __restrict__ a2,
                                                 unsigned short* __restrict__ whB,
                                                 float* __restrict__ s1,
                                                 float* __restrict__ s2) {
    __shared__ float hT[64][FIN + 5];   // stride 261 (odd)
    __shared__ float p1[4][64], p2[4][64];
    const int t = threadIdx.x;
    const int i0 = blockIdx.x * 64;
    const int f0 = blockIdx.y * 32;
#pragma unroll
    for (int c = 0; c < 16; ++c) {       // 64x256 floats, float4-coalesced
        int chunk = c * 256 + t;
        int row = chunk >> 6, col = (chunk & 63) * 4;
        f32x4 v = *(const f32x4*)&h[(size_t)(i0 + row) * FIN + col];
        hT[row][col] = v[0]; hT[row][col + 1] = v[1];
        hT[row][col + 2] = v[2]; hT[row][col + 3] = v[3];
    }
    __syncthreads();
    const int lane = t & 63;
    const int wv = t >> 6;
    const int fb8 = __builtin_amdgcn_readfirstlane(f0 + wv * 8); // wave -> 8 f
    const float* w0 = W + (size_t)fb8 * FIN;
    float acc[8] = {0.f, 0.f, 0.f, 0.f, 0.f, 0.f, 0.f, 0.f};
    for (int k = 0; k < FIN; k += 4) {
        float h0 = hT[lane][k],     h1 = hT[lane][k + 1];
        float h2 = hT[lane][k + 2], h3 = hT[lane][k + 3];
#pragma unroll
        for (int c = 0; c < 8; ++c) {
            const float* wr = w0 + c * FIN;   // uniform -> s_load
            acc[c] += h0 * wr[k] + h1 * wr[k + 1] + h2 * wr[k + 2] + h3 * wr[k + 3];
        }
    }
    const int i = i0 + lane;
    float sp1 = 0.f, sp2 = 0.f;
#pragma unroll
    for (int c = 0; c < 8; ++c) {
        whB[whb_idx(i, fb8 + c)] = f2bf(acc[c]);
        sp1 += acc[c] * a1[fb8 + c];          // uniform a -> s_load
        sp2 += acc[c] * a2[fb8 + c];
    }
    p1[wv][lane] = sp1; p2[wv][lane] = sp2;
    __syncthreads();
    if (t < 64) {                              // wave 0 reduces + one atomic each
        float v1 = (p1[0][lane] + p1[1][lane]) + (p1[2][lane] + p1[3][lane]);
        float v2 = (p2[0][lane] + p2[1][lane]) + (p2[2][lane] + p2[3][lane]);
        atomicAdd(&s1[i0 + lane], v1 * LOG2E);
        atomicAdd(&s2[i0 + lane], v2 * LOG2E);
    }
}

// ---------------- Kernel C: fused mask+softmax-partial+PV MFMA ----------------
// grid 1024 (= 256 i-blocks x 4 j-slices), 4 blocks/CU. 32 rows/block.
// adj consumed DIRECTLY as int32 (R1 structure: BW-bound on the 256 MB stream;
// loads at chunk top, consumed immediately -> short VGPR live ranges keep
// 4 blocks/CU resident; prefetch variants measured WORSE (R2: +11 us).
__global__ __launch_bounds__(256) void gat_kernel(const int* __restrict__ adj,
                                                  const unsigned short* __restrict__ whB,
                                                  const float* __restrict__ s1,
                                                  const float* __restrict__ s2,
                                                  float* __restrict__ out,     // slice-0 num
                                                  float* __restrict__ nums,    // slices 1..3
                                                  float* __restrict__ dens) {  // 4 x N
    __shared__ __align__(16) unsigned short sP[MT][KC + 8];
    __shared__ float sDen[MT];
    __shared__ float sS1[MT];
    const int t = threadIdx.x;
    const int slice = blockIdx.x & (JS - 1);
    const int i0 = (blockIdx.x >> 2) * MT;
    const int jb = slice * JW;
    const int kb0 = slice * (JW / 32);
    float* __restrict__ num = slice ? (nums + (size_t)(slice - 1) * N_NODES * FOUT) : out;
    float* __restrict__ den = dens + (size_t)slice * N_NODES;
    if (t < MT) { sDen[t] = 0.f; sS1[t] = s1[i0 + t]; }
    __syncthreads();

    const int r0 = t >> 4;       // 0..15: P rows r0 and r0+16
    const int s  = t & 15;       // 16 consecutive cols [s*16, s*16+16)
    const int lane = t & 63;
    const int quad = lane >> 4;
    const int sl = lane & 15;
    const int wv = t >> 6;       // wave -> 32 features (fb pair wv*2, wv*2+1)
    const int* __restrict__ aRow0 = adj + (size_t)(i0 + r0) * N_NODES + jb;
    const int* __restrict__ aRow1 = aRow0 + (size_t)16 * N_NODES;
    const float s1a = sS1[r0];
    const float s1b = sS1[r0 + 16];

    f32x4 acc00 = {0.f,0.f,0.f,0.f}, acc01 = {0.f,0.f,0.f,0.f};
    f32x4 acc10 = {0.f,0.f,0.f,0.f}, acc11 = {0.f,0.f,0.f,0.f};

    for (int ch = 0; ch < NCHS; ++ch) {
        const int cb = ch * KC + s * 16;   // column base within slice
        // ---- issue this chunk's adj + s2 loads up-front (coalesced 1 KB/16T) --
        i32x4 av0[4], av1[4];
        f32x4 sv[4];
#pragma unroll
        for (int q = 0; q < 4; ++q) {
            av0[q] = *(const i32x4*)&aRow0[cb + q * 4];
            av1[q] = *(const i32x4*)&aRow1[cb + q * 4];
            sv[q]  = *(const f32x4*)&s2[jb + cb + q * 4];
        }
        // ---- build P tile (bf16, exp2 domain) + row-sum partials ----
        float part0 = 0.f, part1 = 0.f;
        unsigned int w0[8], w1[8];
#pragma unroll
        for (int q = 0; q < 4; ++q) {
            float p0[4], p1v[4];
#pragma unroll
            for (int r = 0; r < 4; ++r) {
                float y0 = s1a + sv[q][r];
                float y1 = s1b + sv[q][r];
                y0 = fmaxf(y0, 0.2f * y0);
                y1 = fmaxf(y1, 0.2f * y1);
                float e0 = __builtin_amdgcn_exp2f(y0);
                float e1 = __builtin_amdgcn_exp2f(y1);
                p0[r]  = (av0[q][r] > 0) ? e0 : 0.f;
                p1v[r] = (av1[q][r] > 0) ? e1 : 0.f;
                part0 += p0[r];
                part1 += p1v[r];
            }
            w0[2 * q]     = pack_bf16(p0[0], p0[1]);
            w0[2 * q + 1] = pack_bf16(p0[2], p0[3]);
            w1[2 * q]     = pack_bf16(p1v[0], p1v[1]);
            w1[2 * q + 1] = pack_bf16(p1v[2], p1v[3]);
        }
        // ---- stage P rows as 4x ds_write_b128 ----
        u32x4 ra = {w0[0], w0[1], w0[2], w0[3]};
        u32x4 rb = {w0[4], w0[5], w0[6], w0[7]};
        u32x4 rc = {w1[0], w1[1], w1[2], w1[3]};
        u32x4 rd = {w1[4], w1[5], w1[6], w1[7]};
        *(u32x4*)&sP[r0][s * 16]          = ra;
        *(u32x4*)&sP[r0][s * 16 + 8]      = rb;
        *(u32x4*)&sP[r0 + 16][s * 16]     = rc;
        *(u32x4*)&sP[r0 + 16][s * 16 + 8] = rd;
        // reduce partials across the 16 lanes sharing a row
        part0 += __shfl_xor(part0, 1); part1 += __shfl_xor(part1, 1);
        part0 += __shfl_xor(part0, 2); part1 += __shfl_xor(part1, 2);
        part0 += __shfl_xor(part0, 4); part1 += __shfl_xor(part1, 4);
        part0 += __shfl_xor(part0, 8); part1 += __shfl_xor(part1, 8);
        if (s == 0) { sDen[r0] += part0; sDen[r0 + 16] += part1; }
        __syncthreads();
        // ---- MFMA: NUM[32 x 128] += P[32 x 256] @ Wh[256 x 128] ----
#pragma unroll
        for (int kq = 0; kq < KC / 32; ++kq) {
            bf16x8 a0  = *(const bf16x8*)&sP[sl][kq * 32 + quad * 8];
            bf16x8 a1f = *(const bf16x8*)&sP[16 + sl][kq * 32 + quad * 8];
            int kb = kb0 + ch * (KC / 32) + kq;
            const unsigned short* t0 = whB + ((size_t)(kb * 8 + wv * 2) << 9) + lane * 8;
            bf16x8 b0 = *(const bf16x8*)t0;          // contiguous 1 KB per wave
            bf16x8 b1 = *(const bf16x8*)(t0 + 512);
            acc00 = __builtin_amdgcn_mfma_f32_16x16x32_bf16(a0,  b0, acc00, 0, 0, 0);
            acc01 = __builtin_amdgcn_mfma_f32_16x16x32_bf16(a0,  b1, acc01, 0, 0, 0);
            acc10 = __builtin_amdgcn_mfma_f32_16x16x32_bf16(a1f, b0, acc10, 0, 0, 0);
            acc11 = __builtin_amdgcn_mfma_f32_16x16x32_bf16(a1f, b1, acc11, 0, 0, 0);
        }
        __syncthreads();
    }
    // ---- epilogue: raw partials (divide + ELU in fin_kernel) ----
    if (t < MT) den[i0 + t] = sDen[t];
#pragma unroll
    for (int m = 0; m < 2; ++m) {
#pragma unroll
        for (int nn = 0; nn < 2; ++nn) {
            f32x4 a = (m == 0) ? (nn == 0 ? acc00 : acc01) : (nn == 0 ? acc10 : acc11);
#pragma unroll
            for (int r = 0; r < 4; ++r) {
                int row = m * 16 + quad * 4 + r;     // D row=(lane>>4)*4+reg, col=lane&15
                num[(size_t)(i0 + row) * FOUT + wv * 32 + nn * 16 + sl] = a[r];
            }
        }
    }
}

// ---------------- Kernel D: merge 4 slices, divide, ELU (in-place, x4 vec) ----
__global__ __launch_bounds__(256) void fin_kernel(float* __restrict__ out,      // = num0
                                                  const float* __restrict__ nums,
                                                  const float* __restrict__ dens) {
    const int idx4 = blockIdx.x * 256 + threadIdx.x;   // grid 1024
    const int idx = idx4 * 4;
    const int i = idx >> 7;                            // FOUT = 128 (4 | 128)
    const size_t NF = (size_t)N_NODES * FOUT;
    f32x4 n0 = *(f32x4*)&out[idx];
    f32x4 n1 = *(const f32x4*)&nums[idx];
    f32x4 n2 = *(const f32x4*)&nums[NF + idx];
    f32x4 n3 = *(const f32x4*)&nums[2 * NF + idx];
    float denv = dens[i] + dens[N_NODES + i] + dens[2 * N_NODES + i] + dens[3 * N_NODES + i];
    float dv = fmaxf(denv, 1e-30f);
    f32x4 r;
#pragma unroll
    for (int k = 0; k < 4; ++k) {
        float numv = (n0[k] + n1[k]) + (n2[k] + n3[k]);
        float v = numv / dv;                           // exact div (bit-compat)
        r[k] = (v > 0.f) ? v : expm1f(v);
    }
    *(f32x4*)&out[idx] = r;
}

extern "C" void kernel_launch(void* const* d_in, const int* in_sizes, int n_in,
                              void* d_out, int out_size, void* d_ws, size_t ws_size,
                              hipStream_t stream) {
    const float* h   = (const float*)d_in[0];
    const int*   adj = (const int*)d_in[1];
    const float* W   = (const float*)d_in[2];
    const float* a1  = (const float*)d_in[3];
    const float* a2  = (const float*)d_in[4];

    // d_ws layout (ws is 1 GiB per the harness fill; we use ~17 MB):
    //   [0, 2MB)    whB (bf16, fragment-ordered)
    //   [4MB..)     s1 | s2 | dens(4xN) | nums(3 x N*FOUT)
    char* ws = (char*)d_ws;
    unsigned short* whB = (unsigned short*)ws;
    float* s1   = (float*)(ws + (4u << 20));
    float* s2   = s1 + N_NODES;
    float* dens = s2 + N_NODES;
    float* nums = dens + 4 * N_NODES;
    float* out  = (float*)d_out;

    zs_kernel<<<dim3(16), 256, 0, stream>>>(s1);   // zeros s1|s2 (contiguous)
    wh_kernel<<<dim3(N_NODES / 64, FOUT / 32), 256, 0, stream>>>(h, W, a1, a2,
                                                                 whB, s1, s2);
    gat_kernel<<<dim3((N_NODES / MT) * JS), 256, 0, stream>>>(adj, whB, s1, s2,
                                                              out, nums, dens);
    fin_kernel<<<dim3(N_NODES * FOUT / 1024), 256, 0, stream>>>(out, nums, dens);
}

// Round 4
// 399.289 us; speedup vs baseline: 1.0464x; 1.0106x over previous
//
#include <hip/hip_runtime.h>
#include <cstdint>
#include <cstddef>

// Dtypes PROVEN fp32 (R2 bf16-read -> NaN; R4 fp32-read -> pass, absmax 0.0078).
#define N_NODES 8192
#define FIN 256
#define FOUT 128
#define MT 32                 // rows per block in gat kernel
#define KC 256                // j-chunk size
#define JS 4                  // j slices (partial softmax, merged in fin_kernel)
#define JW (N_NODES / JS)     // 2048 columns per slice
#define NCHS (JW / KC)        // 8 chunks per block
#define LOG2E 1.4426950408889634f

typedef __attribute__((ext_vector_type(8))) short bf16x8;
typedef __attribute__((ext_vector_type(4))) float f32x4;
typedef __attribute__((ext_vector_type(4))) int i32x4;
typedef __attribute__((ext_vector_type(2))) unsigned int u32x2;
typedef __attribute__((ext_vector_type(4))) unsigned int u32x4;

__device__ __forceinline__ float bf2f(unsigned short u) {
    union { unsigned int i; float f; } v; v.i = ((unsigned int)u) << 16; return v.f;
}
__device__ __forceinline__ unsigned short f2bf(float f) {
    union { float f; unsigned int i; } v; v.f = f;
    unsigned int r = (v.i + 0x7FFFu + ((v.i >> 16) & 1u)) >> 16;
    return (unsigned short)r;
}
__device__ __forceinline__ unsigned int pack_bf16(float a, float b) {
    return (unsigned)f2bf(a) | ((unsigned)f2bf(b) << 16);
}

// whB fragment-order layout: tile (kb, fb) holds Wh[j=kb*32+quad*8+e][f=fb*16+sl]
// at element ((kb*8+fb)*512 + (quad*16+sl)*8 + e) -> a wave's B-load is one
// contiguous 1 KB burst.
__device__ __forceinline__ size_t whb_idx(int j, int f) {
    return ((size_t)((j >> 5) * 8 + (f >> 4)) << 9) + (((j >> 3) & 3) << 7)
         + ((f & 15) << 3) + (j & 7);
}

// ---------------- Kernel A: whB = fragment-ordered bf16 (h @ W^T) -------------
// s-pass fused: per-block s1/s2 partials (over this block's 32 f) are
// LDS-reduced across the 4 waves and PLAIN-STORED to s1p/s2p[blockIdx.y][i]
// -> no atomics, no zero-init kernel. gat sums the 4 partials.
__global__ __launch_bounds__(256) void wh_kernel(const float* __restrict__ h,
                                                 const float* __restrict__ W,
                                                 const float* __restrict__ a1,
                                                 const float* __restrict__ a2,
                                                 unsigned short* __restrict__ whB,
                                                 float* __restrict__ s1p,
                                                 float* __restrict__ s2p) {
    __shared__ float hT[64][FIN + 5];   // stride 261 (odd)
    __shared__ float p1[4][64], p2[4][64];
    const int t = threadIdx.x;
    const int i0 = blockIdx.x * 64;
    const int f0 = blockIdx.y * 32;
#pragma unroll
    for (int c = 0; c < 16; ++c) {       // 64x256 floats, float4-coalesced
        int chunk = c * 256 + t;
        int row = chunk >> 6, col = (chunk & 63) * 4;
        f32x4 v = *(const f32x4*)&h[(size_t)(i0 + row) * FIN + col];
        hT[row][col] = v[0]; hT[row][col + 1] = v[1];
        hT[row][col + 2] = v[2]; hT[row][col + 3] = v[3];
    }
    __syncthreads();
    const int lane = t & 63;
    const int wv = t >> 6;
    const int fb8 = __builtin_amdgcn_readfirstlane(f0 + wv * 8); // wave -> 8 f
    const float* w0 = W + (size_t)fb8 * FIN;
    float acc[8] = {0.f, 0.f, 0.f, 0.f, 0.f, 0.f, 0.f, 0.f};
    for (int k = 0; k < FIN; k += 4) {
        float h0 = hT[lane][k],     h1 = hT[lane][k + 1];
        float h2 = hT[lane][k + 2], h3 = hT[lane][k + 3];
#pragma unroll
        for (int c = 0; c < 8; ++c) {
            const float* wr = w0 + c * FIN;   // uniform -> s_load
            acc[c] += h0 * wr[k] + h1 * wr[k + 1] + h2 * wr[k + 2] + h3 * wr[k + 3];
        }
    }
    const int i = i0 + lane;
    float sp1 = 0.f, sp2 = 0.f;
#pragma unroll
    for (int c = 0; c < 8; ++c) {
        whB[whb_idx(i, fb8 + c)] = f2bf(acc[c]);
        sp1 += acc[c] * a1[fb8 + c];          // uniform a -> s_load
        sp2 += acc[c] * a2[fb8 + c];
    }
    p1[wv][lane] = sp1; p2[wv][lane] = sp2;
    __syncthreads();
    if (t < 64) {                              // wave 0 reduces + plain stores
        float v1 = (p1[0][lane] + p1[1][lane]) + (p1[2][lane] + p1[3][lane]);
        float v2 = (p2[0][lane] + p2[1][lane]) + (p2[2][lane] + p2[3][lane]);
        s1p[(size_t)blockIdx.y * N_NODES + i0 + lane] = v1 * LOG2E;
        s2p[(size_t)blockIdx.y * N_NODES + i0 + lane] = v2 * LOG2E;
    }
}

// ---------------- Kernel C: fused mask+softmax-partial+PV MFMA ----------------
// grid 1024 (= 256 i-blocks x 4 j-slices), 4 blocks/CU. 32 rows/block.
// adj consumed DIRECTLY as int32 (R1 structure: BW-bound on the 256 MB stream;
// loads at chunk top, consumed immediately -> short VGPR live ranges; prefetch
// variants measured WORSE (R2: +11 us). s2 partials summed ONCE into LDS at
// block start; per-chunk sv is a ds_read_b128 (no global loads, -16 VGPR).
__global__ __launch_bounds__(256) void gat_kernel(const int* __restrict__ adj,
                                                  const unsigned short* __restrict__ whB,
                                                  const float* __restrict__ s1p,
                                                  const float* __restrict__ s2p,
                                                  float* __restrict__ out,     // slice-0 num
                                                  float* __restrict__ nums,    // slices 1..3
                                                  float* __restrict__ dens) {  // 4 x N
    __shared__ __align__(16) unsigned short sP[MT][KC + 8];
    __shared__ __align__(16) float sS2[JW / 1];   // slice-local 2048 cols, 8 KB
    __shared__ float sDen[MT];
    __shared__ float sS1[MT];
    const int t = threadIdx.x;
    const int slice = blockIdx.x & (JS - 1);
    const int i0 = (blockIdx.x >> 2) * MT;
    const int jb = slice * JW;
    const int kb0 = slice * (JW / 32);
    float* __restrict__ num = slice ? (nums + (size_t)(slice - 1) * N_NODES * FOUT) : out;
    float* __restrict__ den = dens + (size_t)slice * N_NODES;

    // ---- sum 4 s2 partials into sS2 (32 KB L2-hit reads, once per block) ----
    {
        const float* p0 = s2p + jb + t * 8;
        f32x4 a = {0.f, 0.f, 0.f, 0.f}, b = {0.f, 0.f, 0.f, 0.f};
#pragma unroll
        for (int pb = 0; pb < 4; ++pb) {
            a += *(const f32x4*)(p0 + (size_t)pb * N_NODES);
            b += *(const f32x4*)(p0 + (size_t)pb * N_NODES + 4);
        }
        *(f32x4*)&sS2[t * 8]     = a;
        *(f32x4*)&sS2[t * 8 + 4] = b;
    }
    if (t < MT) {
        float a = 0.f;
#pragma unroll
        for (int pb = 0; pb < 4; ++pb) a += s1p[(size_t)pb * N_NODES + i0 + t];
        sS1[t] = a;
        sDen[t] = 0.f;
    }
    __syncthreads();

    const int r0 = t >> 4;       // 0..15: P rows r0 and r0+16
    const int s  = t & 15;       // 16 consecutive cols [s*16, s*16+16)
    const int lane = t & 63;
    const int quad = lane >> 4;
    const int sl = lane & 15;
    const int wv = t >> 6;       // wave -> 32 features (fb pair wv*2, wv*2+1)
    const int* __restrict__ aRow0 = adj + (size_t)(i0 + r0) * N_NODES + jb;
    const int* __restrict__ aRow1 = aRow0 + (size_t)16 * N_NODES;
    const float s1a = sS1[r0];
    const float s1b = sS1[r0 + 16];

    f32x4 acc00 = {0.f,0.f,0.f,0.f}, acc01 = {0.f,0.f,0.f,0.f};
    f32x4 acc10 = {0.f,0.f,0.f,0.f}, acc11 = {0.f,0.f,0.f,0.f};

    for (int ch = 0; ch < NCHS; ++ch) {
        const int cb = ch * KC + s * 16;   // column base within slice
        // ---- this chunk's adj loads (coalesced 1 KB/16T) + s2 from LDS ----
        i32x4 av0[4], av1[4];
        f32x4 sv[4];
#pragma unroll
        for (int q = 0; q < 4; ++q) {
            av0[q] = *(const i32x4*)&aRow0[cb + q * 4];
            av1[q] = *(const i32x4*)&aRow1[cb + q * 4];
            sv[q]  = *(const f32x4*)&sS2[cb + q * 4];
        }
        // ---- build P tile (bf16, exp2 domain) + row-sum partials ----
        float part0 = 0.f, part1 = 0.f;
        unsigned int w0[8], w1[8];
#pragma unroll
        for (int q = 0; q < 4; ++q) {
            float p0[4], p1v[4];
#pragma unroll
            for (int r = 0; r < 4; ++r) {
                float y0 = s1a + sv[q][r];
                float y1 = s1b + sv[q][r];
                y0 = fmaxf(y0, 0.2f * y0);
                y1 = fmaxf(y1, 0.2f * y1);
                float e0 = __builtin_amdgcn_exp2f(y0);
                float e1 = __builtin_amdgcn_exp2f(y1);
                p0[r]  = (av0[q][r] > 0) ? e0 : 0.f;
                p1v[r] = (av1[q][r] > 0) ? e1 : 0.f;
                part0 += p0[r];
                part1 += p1v[r];
            }
            w0[2 * q]     = pack_bf16(p0[0], p0[1]);
            w0[2 * q + 1] = pack_bf16(p0[2], p0[3]);
            w1[2 * q]     = pack_bf16(p1v[0], p1v[1]);
            w1[2 * q + 1] = pack_bf16(p1v[2], p1v[3]);
        }
        // ---- stage P rows as 4x ds_write_b128 ----
        u32x4 ra = {w0[0], w0[1], w0[2], w0[3]};
        u32x4 rb = {w0[4], w0[5], w0[6], w0[7]};
        u32x4 rc = {w1[0], w1[1], w1[2], w1[3]};
        u32x4 rd = {w1[4], w1[5], w1[6], w1[7]};
        *(u32x4*)&sP[r0][s * 16]          = ra;
        *(u32x4*)&sP[r0][s * 16 + 8]      = rb;
        *(u32x4*)&sP[r0 + 16][s * 16]     = rc;
        *(u32x4*)&sP[r0 + 16][s * 16 + 8] = rd;
        // reduce partials across the 16 lanes sharing a row
        part0 += __shfl_xor(part0, 1); part1 += __shfl_xor(part1, 1);
        part0 += __shfl_xor(part0, 2); part1 += __shfl_xor(part1, 2);
        part0 += __shfl_xor(part0, 4); part1 += __shfl_xor(part1, 4);
        part0 += __shfl_xor(part0, 8); part1 += __shfl_xor(part1, 8);
        if (s == 0) { sDen[r0] += part0; sDen[r0 + 16] += part1; }
        __syncthreads();
        // ---- MFMA: NUM[32 x 128] += P[32 x 256] @ Wh[256 x 128] ----
#pragma unroll
        for (int kq = 0; kq < KC / 32; ++kq) {
            bf16x8 a0  = *(const bf16x8*)&sP[sl][kq * 32 + quad * 8];
            bf16x8 a1f = *(const bf16x8*)&sP[16 + sl][kq * 32 + quad * 8];
            int kb = kb0 + ch * (KC / 32) + kq;
            const unsigned short* t0 = whB + ((size_t)(kb * 8 + wv * 2) << 9) + lane * 8;
            bf16x8 b0 = *(const bf16x8*)t0;          // contiguous 1 KB per wave
            bf16x8 b1 = *(const bf16x8*)(t0 + 512);
            acc00 = __builtin_amdgcn_mfma_f32_16x16x32_bf16(a0,  b0, acc00, 0, 0, 0);
            acc01 = __builtin_amdgcn_mfma_f32_16x16x32_bf16(a0,  b1, acc01, 0, 0, 0);
            acc10 = __builtin_amdgcn_mfma_f32_16x16x32_bf16(a1f, b0, acc10, 0, 0, 0);
            acc11 = __builtin_amdgcn_mfma_f32_16x16x32_bf16(a1f, b1, acc11, 0, 0, 0);
        }
        __syncthreads();
    }
    // ---- epilogue: raw partials (divide + ELU in fin_kernel) ----
    if (t < MT) den[i0 + t] = sDen[t];
#pragma unroll
    for (int m = 0; m < 2; ++m) {
#pragma unroll
        for (int nn = 0; nn < 2; ++nn) {
            f32x4 a = (m == 0) ? (nn == 0 ? acc00 : acc01) : (nn == 0 ? acc10 : acc11);
#pragma unroll
            for (int r = 0; r < 4; ++r) {
                int row = m * 16 + quad * 4 + r;     // D row=(lane>>4)*4+reg, col=lane&15
                num[(size_t)(i0 + row) * FOUT + wv * 32 + nn * 16 + sl] = a[r];
            }
        }
    }
}

// ---------------- Kernel D: merge 4 slices, divide, ELU (in-place, x4 vec) ----
__global__ __launch_bounds__(256) void fin_kernel(float* __restrict__ out,      // = num0
                                                  const float* __restrict__ nums,
                                                  const float* __restrict__ dens) {
    const int idx4 = blockIdx.x * 256 + threadIdx.x;   // grid 1024
    const int idx = idx4 * 4;
    const int i = idx >> 7;                            // FOUT = 128 (4 | 128)
    const size_t NF = (size_t)N_NODES * FOUT;
    f32x4 n0 = *(f32x4*)&out[idx];
    f32x4 n1 = *(const f32x4*)&nums[idx];
    f32x4 n2 = *(const f32x4*)&nums[NF + idx];
    f32x4 n3 = *(const f32x4*)&nums[2 * NF + idx];
    float denv = dens[i] + dens[N_NODES + i] + dens[2 * N_NODES + i] + dens[3 * N_NODES + i];
    float dv = fmaxf(denv, 1e-30f);
    f32x4 r;
#pragma unroll
    for (int k = 0; k < 4; ++k) {
        float numv = (n0[k] + n1[k]) + (n2[k] + n3[k]);
        float v = numv / dv;                           // exact div (bit-compat)
        r[k] = (v > 0.f) ? v : expm1f(v);
    }
    *(f32x4*)&out[idx] = r;
}

extern "C" void kernel_launch(void* const* d_in, const int* in_sizes, int n_in,
                              void* d_out, int out_size, void* d_ws, size_t ws_size,
                              hipStream_t stream) {
    const float* h   = (const float*)d_in[0];
    const int*   adj = (const int*)d_in[1];
    const float* W   = (const float*)d_in[2];
    const float* a1  = (const float*)d_in[3];
    const float* a2  = (const float*)d_in[4];

    // d_ws layout (ws is 1 GiB per the harness fill; we use ~17 MB):
    //   [0, 2MB)    whB (bf16, fragment-ordered)
    //   [4MB..)     s1p(4xN) | s2p(4xN) | dens(4xN) | nums(3 x N*FOUT)
    char* ws = (char*)d_ws;
    unsigned short* whB = (unsigned short*)ws;
    float* s1p  = (float*)(ws + (4u << 20));
    float* s2p  = s1p + 4 * N_NODES;
    float* dens = s2p + 4 * N_NODES;
    float* nums = dens + 4 * N_NODES;
    float* out  = (float*)d_out;

    wh_kernel<<<dim3(N_NODES / 64, FOUT / 32), 256, 0, stream>>>(h, W, a1, a2,
                                                                 whB, s1p, s2p);
    gat_kernel<<<dim3((N_NODES / MT) * JS), 256, 0, stream>>>(adj, whB, s1p, s2p,
                                                              out, nums, dens);
    fin_kernel<<<dim3(N_NODES * FOUT / 1024), 256, 0, stream>>>(out, nums, dens);
}